// Round 1
// baseline (803.981 us; speedup 1.0000x reference)
//
#include <hip/hip_runtime.h>

#define N_NODES 100000
#define N_EDGES 1600000
#define EMBED_DIM 64

#define RPB 256                                   // rows per bucket
#define NBKT ((N_NODES + RPB - 1) / RPB)          // 391
#define CAP 4608                                  // slots per bucket (mean 4092, +8 sigma)
#define TILE 4096                                 // edges per binA block
#define NTILE ((N_EDGES + TILE - 1) / TILE)       // 391
#define OVCAP 8192                                // overflow backstop

// ---------- pass A: tile counting-sort into bucket regions (dense writes) ----------
__global__ __launch_bounds__(256) void k_binA(const int* __restrict__ rows,
                                              const int* __restrict__ cols,
                                              const float* __restrict__ vals,
                                              int* __restrict__ gcur,
                                              int2* __restrict__ packed,
                                              int* __restrict__ ov_cnt,
                                              int4* __restrict__ ov) {
    __shared__ int hist[NBKT];
    __shared__ int off[NBKT];
    __shared__ int cur[NBKT];
    __shared__ int gbase[NBKT];
    __shared__ int ssum[256];
    __shared__ int2 stage[TILE];   // 32 KB
    __shared__ int dg[TILE];       // 16 KB
    const int tid = threadIdx.x;
    const int e0 = blockIdx.x * TILE;

    for (int i = tid; i < NBKT; i += 256) hist[i] = 0;
    __syncthreads();

    // pass 1: bucket histogram of this tile
    for (int i = tid; i < TILE; i += 256) {
        int e = e0 + i;
        if (e < N_EDGES) atomicAdd(&hist[rows[e] >> 8], 1);
    }
    __syncthreads();

    // exclusive scan over NBKT (2 items/thread, Hillis-Steele on partials)
    int b0 = 2 * tid, b1 = 2 * tid + 1;
    int h0 = (b0 < NBKT) ? hist[b0] : 0;
    int h1 = (b1 < NBKT) ? hist[b1] : 0;
    ssum[tid] = h0 + h1;
    __syncthreads();
    for (int o = 1; o < 256; o <<= 1) {
        int a = ssum[tid];
        int add = (tid >= o) ? ssum[tid - o] : 0;
        __syncthreads();
        ssum[tid] = a + add;
        __syncthreads();
    }
    int base = (tid == 0) ? 0 : ssum[tid - 1];
    if (b0 < NBKT) { off[b0] = base; cur[b0] = base; }
    if (b1 < NBKT) { off[b1] = base + h0; cur[b1] = base + h0; }

    // bulk global reservation: one atomic per non-empty bucket
    for (int b = tid; b < NBKT; b += 256) {
        int c = hist[b];
        gbase[b] = c ? atomicAdd(&gcur[b], c) : 0;
    }
    __syncthreads();

    // pass 2: place edges grouped-by-bucket into LDS staging
    for (int i = tid; i < TILE; i += 256) {
        int e = e0 + i;
        if (e < N_EDGES) {
            int r = rows[e];
            int b = r >> 8;
            int p = atomicAdd(&cur[b], 1);
            stage[p] = make_int2(((r & (RPB - 1)) << 17) | cols[e],
                                 __float_as_int(vals[e]));
            int d = gbase[b] + (p - off[b]);
            dg[p] = (d < CAP) ? (b * CAP + d) : (0x40000000 | b);
        }
    }
    __syncthreads();

    // flush: consecutive staged elements -> consecutive global slots (dense lines)
    int total = ssum[255];
    for (int j = tid; j < total; j += 256) {
        int d = dg[j];
        int2 ev = stage[j];
        if (d & 0x40000000) {  // overflow backstop (statistically never)
            int b = d & 0xFFFF;
            int ovi = atomicAdd(ov_cnt, 1);
            if (ovi < OVCAP) {
                int r = b * RPB + (((unsigned)ev.x) >> 17);
                ov[ovi] = make_int4(r, ev.x & 0x1FFFF, ev.y, 0);
            }
        } else {
            packed[d] = ev;
        }
    }
}

// ---------- fused accumulate: one block per bucket, 256x64 fp32 LDS accumulator ----------
// Replaces k_binB (row sort) + k_gather (wave-per-row): edges need only be
// bucket-grouped, not row-sorted. acc[r_local*64 + lane] -> bank = lane&31,
// 2-way aliasing (free). 64KB LDS -> 2 blocks/CU, 1024 thr -> 32 waves/CU.
__global__ __launch_bounds__(1024) void k_accum(const float* __restrict__ x,
                                                const int* __restrict__ gcur,
                                                const int* __restrict__ pw,
                                                float* __restrict__ out) {
    __shared__ float acc[RPB * EMBED_DIM];   // 64 KB
    const int b = blockIdx.x;
    const int tid = threadIdx.x;
    const int lane = tid & 63;
    const int wid = tid >> 6;                // 0..15

    // zero accumulator (float4 stores)
    {
        float4 z = make_float4(0.f, 0.f, 0.f, 0.f);
        float4* a4 = (float4*)acc;
        for (int i = tid; i < RPB * EMBED_DIM / 4; i += 1024) a4[i] = z;
    }
    __syncthreads();

    int n = gcur[b];
    if (n > CAP) n = CAP;
    const int base = b * CAP;

    // each wave takes 32-edge groups, strided by 16 waves
    const int ngrp = (n + 31) >> 5;
    for (int g = wid; g < ngrp; g += 16) {
        int e0 = g << 5;
        int win = n - e0;
        if (win > 32) win = 32;
        int w = 0;
        if (lane < 2 * win) w = pw[2 * (base + e0) + lane];
        for (int k0 = 0; k0 < win; k0 += 16) {
#pragma unroll
            for (int k = 0; k < 16; ++k) {
                int kk = k0 + k;
                int cpack = __builtin_amdgcn_readlane(w, 2 * kk);
                float v = __int_as_float(__builtin_amdgcn_readlane(w, 2 * kk + 1));
                // lanes beyond win loaded w=0 -> v=0 -> harmless +0 to acc[lane]
                float xv = x[(cpack & 0x1FFFF) * EMBED_DIM + lane];
                atomicAdd(&acc[((((unsigned)cpack) >> 17) << 6) + lane], v * xv);
            }
        }
    }
    __syncthreads();

    // dense write-out: 256 rows x 64 floats = 4096 float4, coalesced
    const int r0 = b * RPB;
    float4* a4 = (float4*)acc;
    for (int i = tid; i < RPB * EMBED_DIM / 4; i += 1024) {
        int r = r0 + (i >> 4);
        if (r < N_NODES) ((float4*)out)[(size_t)r * 16 + (i & 15)] = a4[i];
    }
}

// ---------- overflow cleanup (runs after accum; expected n==0) ----------
__global__ __launch_bounds__(256) void k_overflow(const float* __restrict__ x,
                                                  const int* __restrict__ ov_cnt,
                                                  const int4* __restrict__ ov,
                                                  float* __restrict__ out) {
    int n = *ov_cnt;
    if (n > OVCAP) n = OVCAP;
    int idx = (blockIdx.x * 256 + threadIdx.x) >> 6;
    int lane = threadIdx.x & 63;
    if (idx >= n) return;
    int4 e = ov[idx];
    atomicAdd(&out[e.x * EMBED_DIM + lane],
              __int_as_float(e.z) * x[e.y * EMBED_DIM + lane]);
}

// ---------- fallback (ws too small): atomic scatter ----------
__global__ __launch_bounds__(256) void spmm_scatter_kernel(
    const float* __restrict__ x, const float* __restrict__ vals,
    const int* __restrict__ rows, const int* __restrict__ cols,
    float* __restrict__ out) {
    const int wave_in_block = threadIdx.x >> 6;
    const int lane = threadIdx.x & 63;
    const int e = blockIdx.x * 4 + wave_in_block;
    if (e >= N_EDGES) return;
    const float m = vals[e] * x[cols[e] * EMBED_DIM + lane];
    atomicAdd(&out[rows[e] * EMBED_DIM + lane], m);
}

extern "C" void kernel_launch(void* const* d_in, const int* in_sizes, int n_in,
                              void* d_out, int out_size, void* d_ws, size_t ws_size,
                              hipStream_t stream) {
    const float* x    = (const float*)d_in[0];
    const float* vals = (const float*)d_in[1];
    const int*   rows = (const int*)d_in[2];
    const int*   cols = (const int*)d_in[3];
    float* out = (float*)d_out;

    // ws layout: packed[NBKT*CAP] int2 | ov[OVCAP] int4 | gcur[NBKT] | ov_cnt
    const size_t packed_b = (size_t)NBKT * CAP * 8;         // 14,413,824 (16B-aligned)
    const size_t ov_b     = (size_t)OVCAP * 16;
    const size_t need = packed_b + ov_b + ((size_t)NBKT + 1) * 4;
    if (ws_size < need) {
        hipMemsetAsync(out, 0, (size_t)out_size * sizeof(float), stream);
        spmm_scatter_kernel<<<(N_EDGES + 3) / 4, 256, 0, stream>>>(x, vals, rows, cols, out);
        return;
    }

    int2* packed = (int2*)d_ws;
    int4* ov     = (int4*)((char*)d_ws + packed_b);
    int*  gcur   = (int*)((char*)d_ws + packed_b + ov_b);
    int*  ov_cnt = gcur + NBKT;

    // zero gcur + ov_cnt in one shot (adjacent)
    hipMemsetAsync(gcur, 0, ((size_t)NBKT + 1) * sizeof(int), stream);

    k_binA<<<NTILE, 256, 0, stream>>>(rows, cols, vals, gcur, packed, ov_cnt, ov);
    k_accum<<<NBKT, 1024, 0, stream>>>(x, gcur, (const int*)packed, out);
    k_overflow<<<(OVCAP + 3) / 4, 256, 0, stream>>>(x, ov_cnt, ov, out);
}

// Round 4
// 800.339 us; speedup vs baseline: 1.0046x; 1.0046x over previous
//
#include <hip/hip_runtime.h>

#define N_NODES 100000
#define N_EDGES 1600000
#define EMBED_DIM 64

#define RPB 256                                   // rows per bucket
#define NBKT ((N_NODES + RPB - 1) / RPB)          // 391
#define CAP 4608                                  // slots per bucket (mean 4092, +8 sigma)
#define TILE 4096                                 // edges per binA block
#define NTILE ((N_EDGES + TILE - 1) / TILE)       // 391
#define OVCAP 8192                                // overflow backstop

// ---------- pass A: tile counting-sort into bucket regions (dense writes) ----------
__global__ __launch_bounds__(256) void k_binA(const int* __restrict__ rows,
                                              const int* __restrict__ cols,
                                              const float* __restrict__ vals,
                                              int* __restrict__ gcur,
                                              int2* __restrict__ packed,
                                              int* __restrict__ ov_cnt,
                                              int4* __restrict__ ov) {
    __shared__ int hist[NBKT];
    __shared__ int off[NBKT];
    __shared__ int cur[NBKT];
    __shared__ int gbase[NBKT];
    __shared__ int ssum[256];
    __shared__ int2 stage[TILE];   // 32 KB
    __shared__ int dg[TILE];       // 16 KB
    const int tid = threadIdx.x;
    const int e0 = blockIdx.x * TILE;

    for (int i = tid; i < NBKT; i += 256) hist[i] = 0;
    __syncthreads();

    // pass 1: bucket histogram of this tile
    for (int i = tid; i < TILE; i += 256) {
        int e = e0 + i;
        if (e < N_EDGES) atomicAdd(&hist[rows[e] >> 8], 1);
    }
    __syncthreads();

    // exclusive scan over NBKT (2 items/thread, Hillis-Steele on partials)
    int b0 = 2 * tid, b1 = 2 * tid + 1;
    int h0 = (b0 < NBKT) ? hist[b0] : 0;
    int h1 = (b1 < NBKT) ? hist[b1] : 0;
    ssum[tid] = h0 + h1;
    __syncthreads();
    for (int o = 1; o < 256; o <<= 1) {
        int a = ssum[tid];
        int add = (tid >= o) ? ssum[tid - o] : 0;
        __syncthreads();
        ssum[tid] = a + add;
        __syncthreads();
    }
    int base = (tid == 0) ? 0 : ssum[tid - 1];
    if (b0 < NBKT) { off[b0] = base; cur[b0] = base; }
    if (b1 < NBKT) { off[b1] = base + h0; cur[b1] = base + h0; }

    // bulk global reservation: one atomic per non-empty bucket
    for (int b = tid; b < NBKT; b += 256) {
        int c = hist[b];
        gbase[b] = c ? atomicAdd(&gcur[b], c) : 0;
    }
    __syncthreads();

    // pass 2: place edges grouped-by-bucket into LDS staging
    for (int i = tid; i < TILE; i += 256) {
        int e = e0 + i;
        if (e < N_EDGES) {
            int r = rows[e];
            int b = r >> 8;
            int p = atomicAdd(&cur[b], 1);
            stage[p] = make_int2(((r & (RPB - 1)) << 17) | cols[e],
                                 __float_as_int(vals[e]));
            int d = gbase[b] + (p - off[b]);
            dg[p] = (d < CAP) ? (b * CAP + d) : (0x40000000 | b);
        }
    }
    __syncthreads();

    // flush: consecutive staged elements -> consecutive global slots (dense lines)
    int total = ssum[255];
    for (int j = tid; j < total; j += 256) {
        int d = dg[j];
        int2 ev = stage[j];
        if (d & 0x40000000) {  // overflow backstop (statistically never)
            int b = d & 0xFFFF;
            int ovi = atomicAdd(ov_cnt, 1);
            if (ovi < OVCAP) {
                int r = b * RPB + (((unsigned)ev.x) >> 17);
                ov[ovi] = make_int4(r, ev.x & 0x1FFFF, ev.y, 0);
            }
        } else {
            packed[d] = ev;
        }
    }
}

// ---------- fused accumulate: one block per bucket, 256x64 fp32 LDS accumulator ----------
// Two-phase batched inner loop: 8 independent x-loads issued into register
// arrays FIRST (static indices -> stays in VGPRs), then 8 fire-and-forget
// ds_add_f32. Round-1 version kept only 1 load in flight (VGPR=8, 690us).
// Batch=8 (not 16) + plain __launch_bounds__(512): keeps VGPR well under the
// 256 budget -> NO scratch spill (suspected cause of round-2/3 container
// failures: spill scratch alloc during graph capture).
// acc[r_local*64 + lane]: bank = lane&31 -> 2-way aliasing (free).
// 64KB LDS -> 2 blocks/CU if VGPR<=128, else 1; either way >=8 waves/CU.
__global__ __launch_bounds__(512) void k_accum(const float* __restrict__ x,
                                               const int* __restrict__ gcur,
                                               const int* __restrict__ pw,
                                               float* __restrict__ out) {
    __shared__ float acc[RPB * EMBED_DIM];   // 64 KB
    const int b = blockIdx.x;
    const int tid = threadIdx.x;
    const int lane = tid & 63;
    const int wid = tid >> 6;                // 0..7
    const int NW = 8;

    // zero accumulator (float4 stores)
    {
        float4 z = make_float4(0.f, 0.f, 0.f, 0.f);
        float4* a4 = (float4*)acc;
        for (int i = tid; i < RPB * EMBED_DIM / 4; i += 512) a4[i] = z;
    }
    __syncthreads();

    int n = gcur[b];
    if (n > CAP) n = CAP;
    const int base2 = 2 * (b * CAP);
    const int ngrp = (n + 31) >> 5;

    // each wave takes 32-edge groups, strided by 8 waves; prefetch next w
    int g = wid;
    int w = 0;
    if (g < ngrp) {
        int e0 = g << 5;
        int win = n - e0;
        if (win > 32) win = 32;
        if (lane < 2 * win) w = pw[base2 + (e0 << 1) + lane];
    }
    for (; g < ngrp; g += NW) {
        int e0 = g << 5;
        int win = n - e0;
        if (win > 32) win = 32;

        // prefetch next group's packed-edge word
        int wn = 0;
        int gn = g + NW;
        if (gn < ngrp) {
            int e0n = gn << 5;
            int winn = n - e0n;
            if (winn > 32) winn = 32;
            if (lane < 2 * winn) wn = pw[base2 + (e0n << 1) + lane];
        }

        for (int k0 = 0; k0 < win; k0 += 8) {
            float xv[8], vv[8];
            int ai[8];
#pragma unroll
            for (int k = 0; k < 8; ++k) {
                int kk = k0 + k;
                int cpack = __builtin_amdgcn_readlane(w, 2 * kk);
                vv[k] = __int_as_float(__builtin_amdgcn_readlane(w, 2 * kk + 1));
                // lanes beyond win loaded w=0 -> v=0 -> harmless +0 to acc[lane]
                ai[k] = ((((unsigned)cpack) >> 17) << 6) + lane;
                xv[k] = x[(cpack & 0x1FFFF) * EMBED_DIM + lane];
            }
#pragma unroll
            for (int k = 0; k < 8; ++k) {
                atomicAdd(&acc[ai[k]], vv[k] * xv[k]);
            }
        }
        w = wn;
    }
    __syncthreads();

    // dense write-out: 256 rows x 64 floats = 4096 float4, coalesced
    const int r0 = b * RPB;
    float4* a4 = (float4*)acc;
    for (int i = tid; i < RPB * EMBED_DIM / 4; i += 512) {
        int r = r0 + (i >> 4);
        if (r < N_NODES) ((float4*)out)[(size_t)r * 16 + (i & 15)] = a4[i];
    }
}

// ---------- overflow cleanup (runs after accum; expected n==0) ----------
__global__ __launch_bounds__(256) void k_overflow(const float* __restrict__ x,
                                                  const int* __restrict__ ov_cnt,
                                                  const int4* __restrict__ ov,
                                                  float* __restrict__ out) {
    int n = *ov_cnt;
    if (n > OVCAP) n = OVCAP;
    int idx = (blockIdx.x * 256 + threadIdx.x) >> 6;
    int lane = threadIdx.x & 63;
    if (idx >= n) return;
    int4 e = ov[idx];
    atomicAdd(&out[e.x * EMBED_DIM + lane],
              __int_as_float(e.z) * x[e.y * EMBED_DIM + lane]);
}

// ---------- fallback (ws too small): atomic scatter ----------
__global__ __launch_bounds__(256) void spmm_scatter_kernel(
    const float* __restrict__ x, const float* __restrict__ vals,
    const int* __restrict__ rows, const int* __restrict__ cols,
    float* __restrict__ out) {
    const int wave_in_block = threadIdx.x >> 6;
    const int lane = threadIdx.x & 63;
    const int e = blockIdx.x * 4 + wave_in_block;
    if (e >= N_EDGES) return;
    const float m = vals[e] * x[cols[e] * EMBED_DIM + lane];
    atomicAdd(&out[rows[e] * EMBED_DIM + lane], m);
}

extern "C" void kernel_launch(void* const* d_in, const int* in_sizes, int n_in,
                              void* d_out, int out_size, void* d_ws, size_t ws_size,
                              hipStream_t stream) {
    const float* x    = (const float*)d_in[0];
    const float* vals = (const float*)d_in[1];
    const int*   rows = (const int*)d_in[2];
    const int*   cols = (const int*)d_in[3];
    float* out = (float*)d_out;

    // ws layout: packed[NBKT*CAP] int2 | ov[OVCAP] int4 | gcur[NBKT] | ov_cnt
    const size_t packed_b = (size_t)NBKT * CAP * 8;         // 14,413,824 (16B-aligned)
    const size_t ov_b     = (size_t)OVCAP * 16;
    const size_t need = packed_b + ov_b + ((size_t)NBKT + 1) * 4;
    if (ws_size < need) {
        hipMemsetAsync(out, 0, (size_t)out_size * sizeof(float), stream);
        spmm_scatter_kernel<<<(N_EDGES + 3) / 4, 256, 0, stream>>>(x, vals, rows, cols, out);
        return;
    }

    int2* packed = (int2*)d_ws;
    int4* ov     = (int4*)((char*)d_ws + packed_b);
    int*  gcur   = (int*)((char*)d_ws + packed_b + ov_b);
    int*  ov_cnt = gcur + NBKT;

    // zero gcur + ov_cnt in one shot (adjacent)
    hipMemsetAsync(gcur, 0, ((size_t)NBKT + 1) * sizeof(int), stream);

    k_binA<<<NTILE, 256, 0, stream>>>(rows, cols, vals, gcur, packed, ov_cnt, ov);
    k_accum<<<NBKT, 512, 0, stream>>>(x, gcur, (const int*)packed, out);
    k_overflow<<<(OVCAP + 3) / 4, 256, 0, stream>>>(x, ov_cnt, ov, out);
}

// Round 5
// 172.985 us; speedup vs baseline: 4.6477x; 4.6266x over previous
//
#include <hip/hip_runtime.h>

#define N_NODES 100000
#define N_EDGES 1600000
#define EMBED_DIM 64

#define RPB 256                                   // rows per bucket
#define NBKT ((N_NODES + RPB - 1) / RPB)          // 391
#define CAP 4608                                  // slots per bucket (mean 4092, +8 sigma)
#define TILE 4096                                 // edges per binA block
#define NTILE ((N_EDGES + TILE - 1) / TILE)       // 391
#define OVCAP 8192                                // overflow backstop

// ---------- pass A: tile counting-sort into bucket regions (dense writes) ----------
// 512 threads (8 edges/thread) + wave-shfl scan (3 barriers vs 18 Hillis-Steele).
__global__ __launch_bounds__(512) void k_binA(const int* __restrict__ rows,
                                              const int* __restrict__ cols,
                                              const float* __restrict__ vals,
                                              int* __restrict__ gcur,
                                              int2* __restrict__ packed,
                                              int* __restrict__ ov_cnt,
                                              int4* __restrict__ ov) {
    __shared__ int hist[NBKT];
    __shared__ int off[NBKT];
    __shared__ int cur[NBKT];
    __shared__ int gbase[NBKT];
    __shared__ int wsum[8];
    __shared__ int stotal;
    __shared__ int2 stage[TILE];   // 32 KB
    __shared__ int dg[TILE];       // 16 KB
    const int tid = threadIdx.x;
    const int lane = tid & 63;
    const int wid = tid >> 6;      // 0..7
    const int e0 = blockIdx.x * TILE;

    for (int i = tid; i < NBKT; i += 512) hist[i] = 0;
    __syncthreads();

    // pass 1: bucket histogram of this tile
    for (int i = tid; i < TILE; i += 512) {
        int e = e0 + i;
        if (e < N_EDGES) atomicAdd(&hist[rows[e] >> 8], 1);
    }
    __syncthreads();

    // exclusive scan of hist[0..NBKT-1]: per-wave shfl scan + wave-offset combine
    int v = (tid < NBKT) ? hist[tid] : 0;
    int incl = v;
    for (int o = 1; o < 64; o <<= 1) {
        int t = __shfl_up(incl, o, 64);
        if (lane >= o) incl += t;
    }
    if (lane == 63) wsum[wid] = incl;
    __syncthreads();
    if (wid == 0 && lane < 8) {
        int s = wsum[lane];
        int si = s;
        for (int o = 1; o < 8; o <<= 1) {
            int t = __shfl_up(si, o, 64);
            if (lane >= o) si += t;
        }
        wsum[lane] = si - s;           // exclusive wave offset
        if (lane == 7) stotal = si;    // tile total
    }
    __syncthreads();
    int excl = incl - v + wsum[wid];
    if (tid < NBKT) { off[tid] = excl; cur[tid] = excl; }

    // bulk global reservation: one atomic per non-empty bucket
    for (int b = tid; b < NBKT; b += 512) {
        int c = hist[b];
        gbase[b] = c ? atomicAdd(&gcur[b], c) : 0;
    }
    __syncthreads();

    // pass 2: place edges grouped-by-bucket into LDS staging
    for (int i = tid; i < TILE; i += 512) {
        int e = e0 + i;
        if (e < N_EDGES) {
            int r = rows[e];
            int b = r >> 8;
            int p = atomicAdd(&cur[b], 1);
            stage[p] = make_int2(((r & (RPB - 1)) << 17) | cols[e],
                                 __float_as_int(vals[e]));
            int d = gbase[b] + (p - off[b]);
            dg[p] = (d < CAP) ? (b * CAP + d) : (0x40000000 | b);
        }
    }
    __syncthreads();

    // flush: consecutive staged elements -> consecutive global slots (dense lines)
    int total = stotal;
    for (int j = tid; j < total; j += 512) {
        int d = dg[j];
        int2 ev = stage[j];
        if (d & 0x40000000) {  // overflow backstop (statistically never)
            int b = d & 0xFFFF;
            int ovi = atomicAdd(ov_cnt, 1);
            if (ovi < OVCAP) {
                int r = b * RPB + (((unsigned)ev.x) >> 17);
                ov[ovi] = make_int4(r, ev.x & 0x1FFFF, ev.y, 0);
            }
        } else {
            packed[d] = ev;
        }
    }
}

// ---------- pass B: per-bucket row-sort + row_ptr/cnt emission ----------
// 512 threads (8 edges/thread) + wave-shfl scan (3 barriers vs 16).
__global__ __launch_bounds__(512) void k_binB(const int* __restrict__ gcur,
                                              int2* __restrict__ packed,
                                              int* __restrict__ row_ptr,
                                              int* __restrict__ cnt) {
    __shared__ int2 stage[CAP];    // 36 KB
    __shared__ int h[RPB];
    __shared__ int cur[RPB];
    __shared__ int wsum[4];
    const int b = blockIdx.x;
    const int tid = threadIdx.x;
    const int lane = tid & 63;
    const int wid = tid >> 6;      // 0..7
    int n = gcur[b];
    if (n > CAP) n = CAP;
    const int base = b * CAP;

    if (tid < RPB) h[tid] = 0;
    __syncthreads();
    for (int j = tid; j < n; j += 512) {
        int2 e = packed[base + j];
        stage[j] = e;
        atomicAdd(&h[((unsigned)e.x) >> 17], 1);
    }
    __syncthreads();

    // exclusive scan of h[0..255] with waves 0..3
    int hv = (tid < RPB) ? h[tid] : 0;
    int incl = hv;
    for (int o = 1; o < 64; o <<= 1) {
        int t = __shfl_up(incl, o, 64);
        if (lane >= o) incl += t;
    }
    if (tid < RPB && lane == 63) wsum[wid] = incl;
    __syncthreads();
    if (wid == 0 && lane < 4) {
        int s = wsum[lane];
        int si = s;
        for (int o = 1; o < 4; o <<= 1) {
            int t = __shfl_up(si, o, 64);
            if (lane >= o) si += t;
        }
        wsum[lane] = si - s;   // exclusive wave offset
    }
    __syncthreads();
    if (tid < RPB) {
        int ofs = incl - hv + wsum[wid];
        cur[tid] = ofs;
        int r = b * RPB + tid;
        if (r < N_NODES) {
            row_ptr[r] = base + ofs;
            cnt[r] = hv;
        }
    }
    __syncthreads();

    // in-region row-sorted rewrite (source is LDS -> no RAW hazard)
    for (int j = tid; j < n; j += 512) {
        int2 e = stage[j];
        int lr = ((unsigned)e.x) >> 17;
        int p = atomicAdd(&cur[lr], 1);
        packed[base + p] = e;
    }
}

// ---------- gather: one wave per row; cooperative edge load + readlane ----------
__global__ __launch_bounds__(256) void k_gather(const float* __restrict__ x,
                                                const int* __restrict__ row_ptr,
                                                const int* __restrict__ cnt,
                                                const int* __restrict__ pw,
                                                float* __restrict__ out) {
    int wid = (blockIdx.x * 256 + threadIdx.x) >> 6;
    int lane = threadIdx.x & 63;
    if (wid >= N_NODES) return;
    int beg = row_ptr[wid];
    int deg = cnt[wid];
    float acc = 0.f;
    int done = 0;
    while (done < deg) {
        int win = deg - done;
        if (win > 32) win = 32;
        int w = 0;
        if (lane < 2 * win) w = pw[2 * (beg + done) + lane];
        for (int k0 = 0; k0 < win; k0 += 16) {
#pragma unroll
            for (int k = 0; k < 16; ++k) {
                int kk = k0 + k;
                int cpack = __builtin_amdgcn_readlane(w, 2 * kk);
                float v = __int_as_float(__builtin_amdgcn_readlane(w, 2 * kk + 1));
                acc += v * x[(cpack & 0x1FFFF) * EMBED_DIM + lane];
            }
        }
        done += win;
    }
    out[wid * EMBED_DIM + lane] = acc;
}

// ---------- overflow cleanup (runs after gather; expected n==0) ----------
// 64-block grid-stride (was 2048 blocks that mostly exit instantly).
__global__ __launch_bounds__(256) void k_overflow(const float* __restrict__ x,
                                                  const int* __restrict__ ov_cnt,
                                                  const int4* __restrict__ ov,
                                                  float* __restrict__ out) {
    int n = *ov_cnt;
    if (n > OVCAP) n = OVCAP;
    int lane = threadIdx.x & 63;
    int wglobal = (blockIdx.x * 256 + threadIdx.x) >> 6;
    for (int i = wglobal; i < n; i += 64 * 4) {
        int4 e = ov[i];
        atomicAdd(&out[e.x * EMBED_DIM + lane],
                  __int_as_float(e.z) * x[e.y * EMBED_DIM + lane]);
    }
}

// ---------- fallback (ws too small): atomic scatter ----------
__global__ __launch_bounds__(256) void spmm_scatter_kernel(
    const float* __restrict__ x, const float* __restrict__ vals,
    const int* __restrict__ rows, const int* __restrict__ cols,
    float* __restrict__ out) {
    const int wave_in_block = threadIdx.x >> 6;
    const int lane = threadIdx.x & 63;
    const int e = blockIdx.x * 4 + wave_in_block;
    if (e >= N_EDGES) return;
    const float m = vals[e] * x[cols[e] * EMBED_DIM + lane];
    atomicAdd(&out[rows[e] * EMBED_DIM + lane], m);
}

extern "C" void kernel_launch(void* const* d_in, const int* in_sizes, int n_in,
                              void* d_out, int out_size, void* d_ws, size_t ws_size,
                              hipStream_t stream) {
    const float* x    = (const float*)d_in[0];
    const float* vals = (const float*)d_in[1];
    const int*   rows = (const int*)d_in[2];
    const int*   cols = (const int*)d_in[3];
    float* out = (float*)d_out;

    // ws layout: packed[NBKT*CAP] int2 | ov[OVCAP] int4 | gcur[NBKT] | ov_cnt | row_ptr[N] | cnt[N]
    const size_t packed_b = (size_t)NBKT * CAP * 8;         // 14,413,824 (16B-aligned)
    const size_t ov_b     = (size_t)OVCAP * 16;
    const size_t need = packed_b + ov_b + ((size_t)NBKT + 1 + 2 * (size_t)N_NODES) * 4;
    if (ws_size < need) {
        hipMemsetAsync(out, 0, (size_t)out_size * sizeof(float), stream);
        spmm_scatter_kernel<<<(N_EDGES + 3) / 4, 256, 0, stream>>>(x, vals, rows, cols, out);
        return;
    }

    int2* packed  = (int2*)d_ws;
    int4* ov      = (int4*)((char*)d_ws + packed_b);
    int*  gcur    = (int*)((char*)d_ws + packed_b + ov_b);
    int*  ov_cnt  = gcur + NBKT;
    int*  row_ptr = ov_cnt + 1;
    int*  cnt     = row_ptr + N_NODES;

    // single memset: gcur[NBKT] + ov_cnt adjacent
    hipMemsetAsync(gcur, 0, ((size_t)NBKT + 1) * sizeof(int), stream);

    k_binA<<<NTILE, 512, 0, stream>>>(rows, cols, vals, gcur, packed, ov_cnt, ov);
    k_binB<<<NBKT, 512, 0, stream>>>(gcur, packed, row_ptr, cnt);
    k_gather<<<(N_NODES * 64 + 255) / 256, 256, 0, stream>>>(x, row_ptr, cnt, (const int*)packed, out);
    k_overflow<<<64, 256, 0, stream>>>(x, ov_cnt, ov, out);
}